// Round 6
// baseline (108.069 us; speedup 1.0000x reference)
//
#include <hip/hip_runtime.h>
#include <hip/hip_bf16.h>
#include <string.h>

namespace {
constexpr int kN   = 2048;
constexpr int kT   = 64;
constexpr int kDE  = 64;
constexpr int kSUB = 16;
constexpr float kRcs = 0.3f;
constexpr float kRc  = 0.6f;
constexpr float kPi  = 3.14159265358979323846f;
}

typedef __attribute__((ext_vector_type(8))) short bf16x8;  // MFMA A/B frag (8 bf16)
typedef __attribute__((ext_vector_type(4))) float f32x4;   // MFMA C/D frag

union Frag { bf16x8 v; int i[4]; };

// pack two fp32 -> two bf16 (RNE) in one dword (lo = a, hi = b)
__device__ __forceinline__ int pack2(float a, float b) {
    __hip_bfloat162 h = __float22bfloat162_rn(make_float2(a, b));
    int r; memcpy(&r, &h, 4); return r;
}

// ---------------------------------------------------------------------------
// 512 threads = 8 waves; 2 atoms per wave; 16 atoms/block; grid = 1024
// -> 4 blocks/CU x 8 waves = 32 waves/CU (8/SIMD) for latency hiding.
//  p1: lane=t: r_tilde (fp32) -> arena slot [comp][64]
//  p2: per atom: MFMA 16x16x32_bf16: P[hi][(kblk,a)] = h^T x (r_tilde masked)
//  p3: 16-row batch carries atoms {0,1,0,1}: Q = P_exp x W2t (+ rank-1 b2);
//      rows 8-15 duplicate rows 0-7; Q writes masked to rg<2.
//  p4: per atom: D tiles via MFMA with swapped operands: acc=mfma(A0,At)
//      -> lane holds D[e=Nt*16+c][f=rg*4..+3] = contiguous float4 store.
// ---------------------------------------------------------------------------
__global__ __launch_bounds__(512, 8)
void descriptor_kernel(const float* __restrict__ pos,    // (S,N,3)
                       const float* __restrict__ gW1,    // (3,1,32)
                       const float* __restrict__ gB1,    // (3,32)
                       const float* __restrict__ gW2,    // (3,32,64)
                       const float* __restrict__ gB2,    // (3,64)
                       const int*   __restrict__ types,  // (1,N)
                       const int*   __restrict__ neigh,  // (S,N,T)
                       float*       __restrict__ out)    // (S,N,64,16)
{
    // W2 transposed to [e][k], k = net*32+hi (96 used, 104 row pad)
    __shared__ short sW2t[kDE][104];                    // 13312 B
    __shared__ float sB2[3][kDE];                       // 768 B
    // per-(wave,atom) 1 KiB slot, reused: r_tilde -> (Pbf+Pb) -> Qea
    __shared__ __align__(16) char arena[8][2][1024];    // 16384 B  (total 30464)

    const int tid  = threadIdx.x;
    const int w    = tid >> 6;
    const int lane = tid & 63;
    const int rg   = lane >> 4;   // quad id
    const int c    = lane & 15;

    // ---- stage W2 (bf16, transposed) + b2 ----
    for (int i = tid; i < 3 * 32 * kDE; i += 512) {
        const int net = i >> 11;
        const int hi  = (i >> 6) & 31;
        const int e   = i & 63;
        sW2t[e][net * 32 + hi] = (short)(pack2(gW2[i], 0.0f) & 0xFFFF);
    }
    if (tid < 3 * kDE) sB2[tid >> 6][tid & 63] = gB2[tid];

    // ---- per-lane constants ----
    const bool keep0 = (((c >> 2) & 1) == ((rg == 3) ? 1 : 0));   // Ks=0 blockmask
    const bool keep1 = (((c >> 2) & 1) == 1);                     // Ks=1 blockmask
    const int ones_pk = (c == 0) ? 0x3F803F80 : 0;                // bias-tile A row

    float w1v[3][2], b1v[3][2];
    #pragma unroll
    for (int net = 0; net < 3; ++net)
        #pragma unroll
        for (int hf = 0; hf < 2; ++hf) {
            w1v[net][hf] = gW1[net * 32 + hf * 16 + c];
            b1v[net][hf] = gB1[net * 32 + hf * 16 + c];
        }

    const int atomBase = blockIdx.x * 16 + w * 2;

    // ================= phase 1: r_tilde for 2 atoms (lane = t) =================
    #pragma unroll
    for (int g = 0; g < 2; ++g) {
        const int atom = atomBase + g;
        const int j = neigh[(size_t)atom * kT + lane];
        const float* pj = pos + ((size_t)((atom >> 11) << 11) + j) * 3;
        const float* pn = pos + (size_t)atom * 3;
        float dx = pj[0] - pn[0]; dx -= rintf(dx);
        float dy = pj[1] - pn[1]; dy -= rintf(dy);
        float dz = pj[2] - pn[2]; dz -= rintf(dz);
        float dist = sqrtf(dx * dx + dy * dy + dz * dz);
        dist = fmaxf(dist, 1e-12f);
        const float u = (dist - kRcs) * (1.0f / (kRc - kRcs));
        const float sw = 0.5f * __cosf(kPi * u) + 0.5f;
        const float factor = (dist < kRcs) ? 1.0f : ((dist < kRc) ? sw : 0.0f);
        const float sv = factor / dist;
        const float inv = sv / dist;
        float* rt = (float*)arena[w][g];     // [4 comp][64 t]
        rt[lane]       = sv;
        rt[64 + lane]  = dx * inv;
        rt[128 + lane] = dy * inv;
        rt[192 + lane] = dz * inv;
    }

    // ================= phase 2: per-atom P via MFMA =================
    #pragma unroll
    for (int g = 0; g < 2; ++g) {
        const int ty = types[(atomBase + g) & (kN - 1)];
        const float wA0 = ty ? w1v[1][0] : w1v[0][0];
        const float wA1 = ty ? w1v[1][1] : w1v[0][1];
        const float bA0 = ty ? b1v[1][0] : b1v[0][0];
        const float bA1 = ty ? b1v[1][1] : b1v[0][1];
        const float wB0 = ty ? w1v[2][0] : w1v[1][0];
        const float wB1 = ty ? w1v[2][1] : w1v[1][1];
        const float bB0 = ty ? b1v[2][0] : b1v[1][0];
        const float bB1 = ty ? b1v[2][1] : b1v[1][1];

        const float* rt = (const float*)arena[w][g];
        f32x4 acc0 = {0.f, 0.f, 0.f, 0.f};
        f32x4 acc1 = {0.f, 0.f, 0.f, 0.f};
        f32x4 accB = {0.f, 0.f, 0.f, 0.f};

        #pragma unroll
        for (int Ks = 0; Ks < 2; ++Ks) {
            const int tb = Ks * 32 + rg * 8;
            const float4 s0 = *(const float4*)(rt + tb);
            const float4 s1 = *(const float4*)(rt + tb + 4);
            const float4 r0 = *(const float4*)(rt + (c & 3) * 64 + tb);
            const float4 r1 = *(const float4*)(rt + (c & 3) * 64 + tb + 4);
            const bool kp = Ks ? keep1 : keep0;
            Frag B;
            B.i[0] = kp ? pack2(r0.x, r0.y) : 0;
            B.i[1] = kp ? pack2(r0.z, r0.w) : 0;
            B.i[2] = kp ? pack2(r1.x, r1.y) : 0;
            B.i[3] = kp ? pack2(r1.z, r1.w) : 0;

            const bool useA = (Ks == 0) && (rg < 3);
            const float w0 = useA ? wA0 : wB0, b0 = useA ? bA0 : bB0;
            const float w1_ = useA ? wA1 : wB1, b1_ = useA ? bA1 : bB1;

            Frag A0, A1;
            {
                const float h0 = fmaxf(fmaf(s0.x, w0, b0), 0.f);
                const float h1 = fmaxf(fmaf(s0.y, w0, b0), 0.f);
                const float h2 = fmaxf(fmaf(s0.z, w0, b0), 0.f);
                const float h3 = fmaxf(fmaf(s0.w, w0, b0), 0.f);
                const float h4 = fmaxf(fmaf(s1.x, w0, b0), 0.f);
                const float h5 = fmaxf(fmaf(s1.y, w0, b0), 0.f);
                const float h6 = fmaxf(fmaf(s1.z, w0, b0), 0.f);
                const float h7 = fmaxf(fmaf(s1.w, w0, b0), 0.f);
                A0.i[0] = pack2(h0, h1); A0.i[1] = pack2(h2, h3);
                A0.i[2] = pack2(h4, h5); A0.i[3] = pack2(h6, h7);
            }
            {
                const float h0 = fmaxf(fmaf(s0.x, w1_, b1_), 0.f);
                const float h1 = fmaxf(fmaf(s0.y, w1_, b1_), 0.f);
                const float h2 = fmaxf(fmaf(s0.z, w1_, b1_), 0.f);
                const float h3 = fmaxf(fmaf(s0.w, w1_, b1_), 0.f);
                const float h4 = fmaxf(fmaf(s1.x, w1_, b1_), 0.f);
                const float h5 = fmaxf(fmaf(s1.y, w1_, b1_), 0.f);
                const float h6 = fmaxf(fmaf(s1.z, w1_, b1_), 0.f);
                const float h7 = fmaxf(fmaf(s1.w, w1_, b1_), 0.f);
                A1.i[0] = pack2(h0, h1); A1.i[1] = pack2(h2, h3);
                A1.i[2] = pack2(h4, h5); A1.i[3] = pack2(h6, h7);
            }
            Frag Ab; Ab.i[0] = ones_pk; Ab.i[1] = ones_pk; Ab.i[2] = ones_pk; Ab.i[3] = ones_pk;

            acc0 = __builtin_amdgcn_mfma_f32_16x16x32_bf16(A0.v, B.v, acc0, 0, 0, 0);
            acc1 = __builtin_amdgcn_mfma_f32_16x16x32_bf16(A1.v, B.v, acc1, 0, 0, 0);
            accB = __builtin_amdgcn_mfma_f32_16x16x32_bf16(Ab.v, B.v, accB, 0, 0, 0);
        }

        // writeback: slot -> Pbf [a][net][40 hi-pad] bf16 (+ Pb fp32 at 960)
        short* pbf = (short*)arena[w][g];
        if (c < 8) {
            const int kb = c >> 2, a = c & 3;
            short* p = pbf + a * 120 + (ty + kb) * 40;
            *(int*)(p + rg * 4)      = pack2(acc0[0], acc0[1]);
            *(int*)(p + rg * 4 + 2)  = pack2(acc0[2], acc0[3]);
            *(int*)(p + 16 + rg * 4)     = pack2(acc1[0], acc1[1]);
            *(int*)(p + 16 + rg * 4 + 2) = pack2(acc1[2], acc1[3]);
            if (rg == 0) ((float*)(arena[w][g] + 960))[kb * 4 + a] = accB[0];  // Pb
        }
        // zero the inactive net slab (hi 0..31 for all 4 a)
        const int netz = ty ? 0 : 2;
        *(int*)(pbf + rg * 120 + netz * 40 + c * 2) = 0;
    }

    __syncthreads();   // sW2t / sB2 ready (only barrier)

    // ================= phase 3: Q via MFMA (atoms {0,1,0,1} in M rows) =========
    Frag A3_0, A3_1, A3_2;
    {
        const short* base = (const short*)arena[w][(c >> 2) & 1] + (c & 3) * 120 + rg * 8;
        A3_0.v = *(const bf16x8*)(base);
        A3_1.v = *(const bf16x8*)(base + 40);
        A3_2.v = *(const bf16x8*)(base + 80);
    }
    f32x4 q0 = {0.f,0.f,0.f,0.f}, q1 = {0.f,0.f,0.f,0.f};
    f32x4 q2 = {0.f,0.f,0.f,0.f}, q3 = {0.f,0.f,0.f,0.f};
    #pragma unroll
    for (int Nt = 0; Nt < 4; ++Nt) {
        const int e = Nt * 16 + c;
        f32x4 acc = {0.f,0.f,0.f,0.f};
        acc = __builtin_amdgcn_mfma_f32_16x16x32_bf16(A3_0.v, *(const bf16x8*)&sW2t[e][rg * 8],      acc, 0, 0, 0);
        acc = __builtin_amdgcn_mfma_f32_16x16x32_bf16(A3_1.v, *(const bf16x8*)&sW2t[e][32 + rg * 8], acc, 0, 0, 0);
        acc = __builtin_amdgcn_mfma_f32_16x16x32_bf16(A3_2.v, *(const bf16x8*)&sW2t[e][64 + rg * 8], acc, 0, 0, 0);
        if (Nt == 0) q0 = acc; else if (Nt == 1) q1 = acc; else if (Nt == 2) q2 = acc; else q3 = acc;
    }
    // b2 bias: C rows (rg*4+reg) = (atom rg&1, a=reg)
    {
        const int ga = rg & 1;
        const int tyr = types[(atomBase + ga) & (kN - 1)];
        #pragma unroll
        for (int kb = 0; kb < 2; ++kb) {
            const float4 pb = *(const float4*)(arena[w][ga] + 960 + kb * 16);
            const float* b2row = sB2[tyr + kb];
            const float v0 = b2row[c], v1 = b2row[16 + c], v2 = b2row[32 + c], v3 = b2row[48 + c];
            q0[0] = fmaf(pb.x, v0, q0[0]); q0[1] = fmaf(pb.y, v0, q0[1]);
            q0[2] = fmaf(pb.z, v0, q0[2]); q0[3] = fmaf(pb.w, v0, q0[3]);
            q1[0] = fmaf(pb.x, v1, q1[0]); q1[1] = fmaf(pb.y, v1, q1[1]);
            q1[2] = fmaf(pb.z, v1, q1[2]); q1[3] = fmaf(pb.w, v1, q1[3]);
            q2[0] = fmaf(pb.x, v2, q2[0]); q2[1] = fmaf(pb.y, v2, q2[1]);
            q2[2] = fmaf(pb.z, v2, q2[2]); q2[3] = fmaf(pb.w, v2, q2[3]);
            q3[0] = fmaf(pb.x, v3, q3[0]); q3[1] = fmaf(pb.y, v3, q3[1]);
            q3[2] = fmaf(pb.z, v3, q3[2]); q3[3] = fmaf(pb.w, v3, q3[3]);
        }
    }
    // write Q as bf16 Qea[e][a] into slot(atom = rg&1); only rg<2 writes
    // (rows 8-15 duplicate rows 0-7). Clobbers Pbf bytes 0..511 — reads done.
    if (rg < 2) {
        short* qslot = (short*)arena[w][rg];
        *(int2*)(qslot + (0 * 16 + c) * 4) = make_int2(pack2(q0[0], q0[1]), pack2(q0[2], q0[3]));
        *(int2*)(qslot + (1 * 16 + c) * 4) = make_int2(pack2(q1[0], q1[1]), pack2(q1[2], q1[3]));
        *(int2*)(qslot + (2 * 16 + c) * 4) = make_int2(pack2(q2[0], q2[1]), pack2(q2[2], q2[3]));
        *(int2*)(qslot + (3 * 16 + c) * 4) = make_int2(pack2(q3[0], q3[1]), pack2(q3[2], q3[3]));
    }

    // ================= phase 4: D tiles via MFMA (swapped operands) ============
    // acc = mfma(A = Qea f-rows, B = Qea e-tile): lane (rg,c) gets
    // D[e=Nt*16+c][f=rg*4+reg] -> one contiguous float4 store per tile.
    #pragma unroll
    for (int g = 0; g < 2; ++g) {
        const short* qs = (const short*)arena[w][g];
        Frag A0;
        {
            int2 qv = make_int2(0, 0);
            if (rg == 0) qv = *(const int2*)(qs + c * 4);
            A0.i[0] = qv.x; A0.i[1] = qv.y; A0.i[2] = 0; A0.i[3] = 0;
        }
        float* ob = out + (size_t)(atomBase + g) * (kDE * kSUB);
        #pragma unroll
        for (int Nt = 0; Nt < 4; ++Nt) {
            Frag At;
            if (Nt == 0) {
                At = A0;
            } else {
                int2 qv = make_int2(0, 0);
                if (rg == 0) qv = *(const int2*)(qs + (Nt * 16 + c) * 4);
                At.i[0] = qv.x; At.i[1] = qv.y; At.i[2] = 0; At.i[3] = 0;
            }
            f32x4 acc = {0.f, 0.f, 0.f, 0.f};
            acc = __builtin_amdgcn_mfma_f32_16x16x32_bf16(A0.v, At.v, acc, 0, 0, 0);
            float* op = ob + (Nt * 16 + c) * kSUB + rg * 4;
            *(float4*)op = make_float4(acc[0], acc[1], acc[2], acc[3]);
        }
    }
}

extern "C" void kernel_launch(void* const* d_in, const int* in_sizes, int n_in,
                              void* d_out, int out_size, void* d_ws, size_t ws_size,
                              hipStream_t stream)
{
    (void)in_sizes; (void)n_in; (void)out_size; (void)d_ws; (void)ws_size;
    const float* pos   = (const float*)d_in[0];
    const float* W1    = (const float*)d_in[1];
    const float* b1    = (const float*)d_in[2];
    const float* W2    = (const float*)d_in[3];
    const float* b2    = (const float*)d_in[4];
    const int*   typesp= (const int*)d_in[5];
    const int*   neigh = (const int*)d_in[6];
    float* out = (float*)d_out;

    const int total_atoms = 8 * kN;               // 16384
    dim3 grid(total_atoms / 16), block(512);      // 1024 blocks x 8 waves x 2 atoms
    hipLaunchKernelGGL(descriptor_kernel, grid, block, 0, stream,
                       pos, W1, b1, W2, b2, typesp, neigh, out);
}

// Round 7
// 98.419 us; speedup vs baseline: 1.0981x; 1.0981x over previous
//
#include <hip/hip_runtime.h>
#include <hip/hip_bf16.h>
#include <string.h>

namespace {
constexpr int kN   = 2048;
constexpr int kT   = 64;
constexpr int kDE  = 64;
constexpr int kSUB = 16;
constexpr float kRcs = 0.3f;
constexpr float kRc  = 0.6f;
constexpr float kPi  = 3.14159265358979323846f;
}

typedef __attribute__((ext_vector_type(8))) short bf16x8;  // MFMA A/B frag (8 bf16)
typedef __attribute__((ext_vector_type(4))) float f32x4;   // MFMA C/D frag
typedef __attribute__((ext_vector_type(2))) float f32x2;   // packed-fp32 (v_pk_*)

union Frag { bf16x8 v; int i[4]; };

// pack two fp32 -> two bf16 (RNE) in one dword (lo = a, hi = b)
__device__ __forceinline__ int pack2(float a, float b) {
    __hip_bfloat162 h = __float22bfloat162_rn(make_float2(a, b));
    int r; memcpy(&r, &h, 4); return r;
}

// h pair: relu(fma(s, w, b)) via packed fp32 (v_pk_fma_f32 / v_pk_max_f32),
// then pack to bf16x2 dword.
__device__ __forceinline__ int packh(f32x2 s, f32x2 wv, f32x2 bv) {
    f32x2 h = __builtin_elementwise_fma(s, wv, bv);
    h = __builtin_elementwise_max(h, (f32x2)(0.0f));
    return pack2(h.x, h.y);
}

// ---------------------------------------------------------------------------
// 256 threads = 4 waves; 4 atoms per wave; 16 atoms/block; grid = 1024.
//  p1: lane=t: r_tilde (fp32) -> arena slot [comp][64]
//  p2: per atom: MFMA 16x16x32_bf16: P[hi][(kblk,a)] = h^T x (r_tilde masked)
//      h built with packed-fp32 fma/max.
//  p3: batched 4 atoms: Q[(atom,a)][e] = P_exp x W2t (+ rank-1 b2 bias);
//      Q packed bf16 -> slot as Qea[e][a] (4-short rows)
//  p4: per atom: D tiles via MFMA, swapped operands: acc = mfma(A0, At)
//      -> lane (rg,c) holds D[e=Nt*16+c][f=rg*4..+3] = one float4 store.
// ---------------------------------------------------------------------------
__global__ __launch_bounds__(256, 4)
void descriptor_kernel(const float* __restrict__ pos,    // (S,N,3)
                       const float* __restrict__ gW1,    // (3,1,32)
                       const float* __restrict__ gB1,    // (3,32)
                       const float* __restrict__ gW2,    // (3,32,64)
                       const float* __restrict__ gB2,    // (3,64)
                       const int*   __restrict__ types,  // (1,N)
                       const int*   __restrict__ neigh,  // (S,N,T)
                       float*       __restrict__ out)    // (S,N,64,16)
{
    // W2 transposed to [e][k], k = net*32+hi (96 used, 104 row pad)
    __shared__ short sW2t[kDE][104];                    // 13312 B
    __shared__ float sB2[3][kDE];                       // 768 B
    // per-(wave,atom) 1 KiB slot, reused: r_tilde -> (Pbf+Pb) -> Qea
    __shared__ __align__(16) char arena[4][4][1024];    // 16384 B  (total 30464)

    const int tid  = threadIdx.x;
    const int w    = tid >> 6;
    const int lane = tid & 63;
    const int rg   = lane >> 4;   // quad id
    const int c    = lane & 15;

    // ---- stage W2 (bf16, transposed) + b2 ----
    for (int i = tid; i < 3 * 32 * kDE; i += 256) {
        const int net = i >> 11;
        const int hi  = (i >> 6) & 31;
        const int e   = i & 63;
        sW2t[e][net * 32 + hi] = (short)(pack2(gW2[i], 0.0f) & 0xFFFF);
    }
    if (tid < 3 * kDE) sB2[tid >> 6][tid & 63] = gB2[tid];

    // ---- per-lane constants ----
    const bool keep0 = (((c >> 2) & 1) == ((rg == 3) ? 1 : 0));   // Ks=0 blockmask
    const bool keep1 = (((c >> 2) & 1) == 1);                     // Ks=1 blockmask
    const int ones_pk = (c == 0) ? 0x3F803F80 : 0;                // bias-tile A row

    float w1v[3][2], b1v[3][2];
    #pragma unroll
    for (int net = 0; net < 3; ++net)
        #pragma unroll
        for (int hf = 0; hf < 2; ++hf) {
            w1v[net][hf] = gW1[net * 32 + hf * 16 + c];
            b1v[net][hf] = gB1[net * 32 + hf * 16 + c];
        }

    const int atomBase = blockIdx.x * 16 + w * 4;

    // ================= phase 1: r_tilde for 4 atoms (lane = t) =================
    #pragma unroll
    for (int g = 0; g < 4; ++g) {
        const int atom = atomBase + g;
        const int j = neigh[(size_t)atom * kT + lane];
        const float* pj = pos + ((size_t)((atom >> 11) << 11) + j) * 3;
        const float* pn = pos + (size_t)atom * 3;
        float dx = pj[0] - pn[0]; dx -= rintf(dx);
        float dy = pj[1] - pn[1]; dy -= rintf(dy);
        float dz = pj[2] - pn[2]; dz -= rintf(dz);
        float dist = sqrtf(dx * dx + dy * dy + dz * dz);
        dist = fmaxf(dist, 1e-12f);
        const float u = (dist - kRcs) * (1.0f / (kRc - kRcs));
        const float sw = 0.5f * __cosf(kPi * u) + 0.5f;
        const float factor = (dist < kRcs) ? 1.0f : ((dist < kRc) ? sw : 0.0f);
        const float sv = factor / dist;
        const float inv = sv / dist;
        float* rt = (float*)arena[w][g];     // [4 comp][64 t]
        rt[lane]       = sv;
        rt[64 + lane]  = dx * inv;
        rt[128 + lane] = dy * inv;
        rt[192 + lane] = dz * inv;
    }

    // ================= phase 2: per-atom P via MFMA =================
    #pragma unroll
    for (int g = 0; g < 4; ++g) {
        const int ty = types[(atomBase + g) & (kN - 1)];
        const float wA0 = ty ? w1v[1][0] : w1v[0][0];
        const float wA1 = ty ? w1v[1][1] : w1v[0][1];
        const float bA0 = ty ? b1v[1][0] : b1v[0][0];
        const float bA1 = ty ? b1v[1][1] : b1v[0][1];
        const float wB0 = ty ? w1v[2][0] : w1v[1][0];
        const float wB1 = ty ? w1v[2][1] : w1v[1][1];
        const float bB0 = ty ? b1v[2][0] : b1v[1][0];
        const float bB1 = ty ? b1v[2][1] : b1v[1][1];

        const float* rt = (const float*)arena[w][g];
        f32x4 acc0 = {0.f, 0.f, 0.f, 0.f};
        f32x4 acc1 = {0.f, 0.f, 0.f, 0.f};
        f32x4 accB = {0.f, 0.f, 0.f, 0.f};

        #pragma unroll
        for (int Ks = 0; Ks < 2; ++Ks) {
            const int tb = Ks * 32 + rg * 8;
            const float4 s0 = *(const float4*)(rt + tb);
            const float4 s1 = *(const float4*)(rt + tb + 4);
            const float4 r0 = *(const float4*)(rt + (c & 3) * 64 + tb);
            const float4 r1 = *(const float4*)(rt + (c & 3) * 64 + tb + 4);
            const bool kp = Ks ? keep1 : keep0;
            Frag B;
            B.i[0] = kp ? pack2(r0.x, r0.y) : 0;
            B.i[1] = kp ? pack2(r0.z, r0.w) : 0;
            B.i[2] = kp ? pack2(r1.x, r1.y) : 0;
            B.i[3] = kp ? pack2(r1.z, r1.w) : 0;

            const bool useA = (Ks == 0) && (rg < 3);
            const float w0 = useA ? wA0 : wB0, b0 = useA ? bA0 : bB0;
            const float w1_ = useA ? wA1 : wB1, b1_ = useA ? bA1 : bB1;

            const f32x2 sa = {s0.x, s0.y}, sb = {s0.z, s0.w};
            const f32x2 sc = {s1.x, s1.y}, sd = {s1.z, s1.w};
            Frag A0, A1;
            {
                const f32x2 wv = {w0, w0}, bv = {b0, b0};
                A0.i[0] = packh(sa, wv, bv); A0.i[1] = packh(sb, wv, bv);
                A0.i[2] = packh(sc, wv, bv); A0.i[3] = packh(sd, wv, bv);
            }
            {
                const f32x2 wv = {w1_, w1_}, bv = {b1_, b1_};
                A1.i[0] = packh(sa, wv, bv); A1.i[1] = packh(sb, wv, bv);
                A1.i[2] = packh(sc, wv, bv); A1.i[3] = packh(sd, wv, bv);
            }
            Frag Ab; Ab.i[0] = ones_pk; Ab.i[1] = ones_pk; Ab.i[2] = ones_pk; Ab.i[3] = ones_pk;

            acc0 = __builtin_amdgcn_mfma_f32_16x16x32_bf16(A0.v, B.v, acc0, 0, 0, 0);
            acc1 = __builtin_amdgcn_mfma_f32_16x16x32_bf16(A1.v, B.v, acc1, 0, 0, 0);
            accB = __builtin_amdgcn_mfma_f32_16x16x32_bf16(Ab.v, B.v, accB, 0, 0, 0);
        }

        // writeback: slot -> Pbf [a][net][40 hi-pad] bf16 (+ Pb fp32 at 960)
        short* pbf = (short*)arena[w][g];
        if (c < 8) {
            const int kb = c >> 2, a = c & 3;
            short* p = pbf + a * 120 + (ty + kb) * 40;
            *(int*)(p + rg * 4)      = pack2(acc0[0], acc0[1]);
            *(int*)(p + rg * 4 + 2)  = pack2(acc0[2], acc0[3]);
            *(int*)(p + 16 + rg * 4)     = pack2(acc1[0], acc1[1]);
            *(int*)(p + 16 + rg * 4 + 2) = pack2(acc1[2], acc1[3]);
            if (rg == 0) ((float*)(arena[w][g] + 960))[kb * 4 + a] = accB[0];  // Pb
        }
        // zero the inactive net slab (hi 0..31 for all 4 a)
        const int netz = ty ? 0 : 2;
        *(int*)(pbf + rg * 120 + netz * 40 + c * 2) = 0;
    }

    __syncthreads();   // sW2t / sB2 ready (only barrier)

    // ================= phase 3: Q for 4 atoms via MFMA =================
    Frag A3_0, A3_1, A3_2;
    {
        const short* base = (const short*)arena[w][c >> 2] + (c & 3) * 120 + rg * 8;
        A3_0.v = *(const bf16x8*)(base);
        A3_1.v = *(const bf16x8*)(base + 40);
        A3_2.v = *(const bf16x8*)(base + 80);
    }
    f32x4 q0 = {0.f,0.f,0.f,0.f}, q1 = {0.f,0.f,0.f,0.f};
    f32x4 q2 = {0.f,0.f,0.f,0.f}, q3 = {0.f,0.f,0.f,0.f};
    #pragma unroll
    for (int Nt = 0; Nt < 4; ++Nt) {
        const int e = Nt * 16 + c;
        f32x4 acc = {0.f,0.f,0.f,0.f};
        acc = __builtin_amdgcn_mfma_f32_16x16x32_bf16(A3_0.v, *(const bf16x8*)&sW2t[e][rg * 8],      acc, 0, 0, 0);
        acc = __builtin_amdgcn_mfma_f32_16x16x32_bf16(A3_1.v, *(const bf16x8*)&sW2t[e][32 + rg * 8], acc, 0, 0, 0);
        acc = __builtin_amdgcn_mfma_f32_16x16x32_bf16(A3_2.v, *(const bf16x8*)&sW2t[e][64 + rg * 8], acc, 0, 0, 0);
        if (Nt == 0) q0 = acc; else if (Nt == 1) q1 = acc; else if (Nt == 2) q2 = acc; else q3 = acc;
    }
    // b2 bias: C rows (rg*4+reg) = (atom rg, a=reg):  q[e] += Pb[kb][a]*b2[ty+kb][e]
    {
        const int tyr = types[(atomBase + rg) & (kN - 1)];
        #pragma unroll
        for (int kb = 0; kb < 2; ++kb) {
            const float4 pb = *(const float4*)(arena[w][rg] + 960 + kb * 16);
            const float* b2row = sB2[tyr + kb];
            const float v0 = b2row[c], v1 = b2row[16 + c], v2 = b2row[32 + c], v3 = b2row[48 + c];
            q0[0] = fmaf(pb.x, v0, q0[0]); q0[1] = fmaf(pb.y, v0, q0[1]);
            q0[2] = fmaf(pb.z, v0, q0[2]); q0[3] = fmaf(pb.w, v0, q0[3]);
            q1[0] = fmaf(pb.x, v1, q1[0]); q1[1] = fmaf(pb.y, v1, q1[1]);
            q1[2] = fmaf(pb.z, v1, q1[2]); q1[3] = fmaf(pb.w, v1, q1[3]);
            q2[0] = fmaf(pb.x, v2, q2[0]); q2[1] = fmaf(pb.y, v2, q2[1]);
            q2[2] = fmaf(pb.z, v2, q2[2]); q2[3] = fmaf(pb.w, v2, q2[3]);
            q3[0] = fmaf(pb.x, v3, q3[0]); q3[1] = fmaf(pb.y, v3, q3[1]);
            q3[2] = fmaf(pb.z, v3, q3[2]); q3[3] = fmaf(pb.w, v3, q3[3]);
        }
    }
    // write Q as bf16 Qea[e][a] (4-short rows) into slot(atom=rg); clobbers Pbf
    // bytes 0..511 -- all Pbf/Pb reads above are done (same-wave DS order).
    {
        short* qslot = (short*)arena[w][rg];
        *(int2*)(qslot + (0 * 16 + c) * 4) = make_int2(pack2(q0[0], q0[1]), pack2(q0[2], q0[3]));
        *(int2*)(qslot + (1 * 16 + c) * 4) = make_int2(pack2(q1[0], q1[1]), pack2(q1[2], q1[3]));
        *(int2*)(qslot + (2 * 16 + c) * 4) = make_int2(pack2(q2[0], q2[1]), pack2(q2[2], q2[3]));
        *(int2*)(qslot + (3 * 16 + c) * 4) = make_int2(pack2(q3[0], q3[1]), pack2(q3[2], q3[3]));
    }

    // ================= phase 4: D tiles via MFMA (swapped operands) ============
    // acc = mfma(A0, At): lane (rg,c) holds D[e=Nt*16+c][f=rg*4+reg]
    // -> one contiguous float4 store per tile (4 dwordx4 stores per atom).
    #pragma unroll
    for (int g = 0; g < 4; ++g) {
        const short* qs = (const short*)arena[w][g];
        Frag A0;
        {
            int2 qv = make_int2(0, 0);
            if (rg == 0) qv = *(const int2*)(qs + c * 4);
            A0.i[0] = qv.x; A0.i[1] = qv.y; A0.i[2] = 0; A0.i[3] = 0;
        }
        float* ob = out + (size_t)(atomBase + g) * (kDE * kSUB);
        #pragma unroll
        for (int Nt = 0; Nt < 4; ++Nt) {
            Frag At;
            if (Nt == 0) {
                At = A0;
            } else {
                int2 qv = make_int2(0, 0);
                if (rg == 0) qv = *(const int2*)(qs + (Nt * 16 + c) * 4);
                At.i[0] = qv.x; At.i[1] = qv.y; At.i[2] = 0; At.i[3] = 0;
            }
            f32x4 acc = {0.f, 0.f, 0.f, 0.f};
            acc = __builtin_amdgcn_mfma_f32_16x16x32_bf16(A0.v, At.v, acc, 0, 0, 0);
            float* op = ob + (Nt * 16 + c) * kSUB + rg * 4;
            *(float4*)op = make_float4(acc[0], acc[1], acc[2], acc[3]);
        }
    }
}

extern "C" void kernel_launch(void* const* d_in, const int* in_sizes, int n_in,
                              void* d_out, int out_size, void* d_ws, size_t ws_size,
                              hipStream_t stream)
{
    (void)in_sizes; (void)n_in; (void)out_size; (void)d_ws; (void)ws_size;
    const float* pos   = (const float*)d_in[0];
    const float* W1    = (const float*)d_in[1];
    const float* b1    = (const float*)d_in[2];
    const float* W2    = (const float*)d_in[3];
    const float* b2    = (const float*)d_in[4];
    const int*   typesp= (const int*)d_in[5];
    const int*   neigh = (const int*)d_in[6];
    float* out = (float*)d_out;

    const int total_atoms = 8 * kN;               // 16384
    dim3 grid(total_atoms / 16), block(256);      // 1024 blocks x 4 waves x 4 atoms
    hipLaunchKernelGGL(descriptor_kernel, grid, block, 0, stream,
                       pos, W1, b1, W2, b2, typesp, neigh, out);
}